// Round 3
// baseline (58.303 us; speedup 1.0000x reference)
//
#include <hip/hip_runtime.h>
#include <math.h>

// ---------------------------------------------------------------------------
// ZBL repulsion, ILP round: 4 pairs/thread.
//  - all loads vectorized (int4 / float4 / 3x float4), no LDS staging
//  - local run-merge on sorted idx_i (rare internal-run atomicAdd),
//    wave segmented reduce once per THREAD (13 bpermutes / 4 pairs)
//  - native exp2/rcp/rsq; rsq gives dist AND 1/dist in one trans op
// ---------------------------------------------------------------------------

#define LOG2E 1.4426950408889634f

static __device__ __forceinline__ float rcpf_(float x)  { return __builtin_amdgcn_rcpf(x); }
static __device__ __forceinline__ float rsqf_(float x)  { return __builtin_amdgcn_rsqf(x); }
static __device__ __forceinline__ float exp2f_(float x) { return __builtin_amdgcn_exp2f(x); }

__global__ void zbl_setup_tab(const float* __restrict__ an,
                              const float* __restrict__ a_exp_ptr,
                              float2* __restrict__ tab, int n) {
    int i = blockIdx.x * blockDim.x + threadIdx.x;
    if (i >= n) return;
    float ae = fabsf(a_exp_ptr[0]);
    float sa = fmaxf(an[i], 1e-6f);
    float z  = expf(logf(sa) * ae);   // one-time, libm precision
    if (!(z == z)) z = 1e-6f;
    z = fminf(z, 1e6f);
    tab[i] = make_float2(z, sa);
}

static __device__ __forceinline__ float pair_rep(
    float dx, float dy, float dz, float bm, float2 ti, float2 tj,
    float ac_inv, float c0, float c1, float c2, float c3,
    float e0, float e1, float e2, float e3)
{
    float d2   = fmaxf(dx * dx + dy * dy + dz * dz, 1e-20f);
    float rsq  = rsqf_(d2);
    float dist = d2 * rsq;                 // sqrt(d2); 1/dist == rsq

    // smooth_switch(dist,0,10) = 1/(1+exp(1/tc - 1/(1-tc)))
    float tt = dist * 0.1f;
    float tc = fminf(fmaxf(tt, 1e-9f), 1.0f - 1e-9f);
    float u  = (1.0f - 2.0f * tc) * rcpf_(tc - tc * tc);
    float s  = rcpf_(1.0f + exp2f_(u * LOG2E));
    float sw = (tt >= 1.0f) ? 1.0f : s;    // tt>0 always since dist>=1e-10

    float za_sum = ti.x + tj.x;
    float arg  = fminf(dist * za_sum * ac_inv, 1e6f);
    float narg = -arg * LOG2E;
    float phi  = c0 * exp2f_(e0 * narg) + c1 * exp2f_(e1 * narg) +
                 c2 * exp2f_(e2 * narg) + c3 * exp2f_(e3 * narg);
    phi = fminf(fmaxf(phi, 1e-30f), 1e6f);

    float cp   = fminf(ti.y * tj.y, 1e4f);
    float brep = fminf(0.5f * cp * rsq, 1e6f);
    float r    = brep * phi * fmaxf(sw, 1e-30f);
    r = fminf(fmaxf(r, 0.0f), 1e6f);
    if (!(r == r)) r = 0.0f;
    return r * bm;
}

__global__ __launch_bounds__(256) void zbl_pair_kernel(
    const float* __restrict__ disp,        // [P*3]
    const int*   __restrict__ idx_i,       // sorted
    const int*   __restrict__ idx_j,
    const float* __restrict__ batch_mask,  // [P]
    const float2* __restrict__ tab,        // {za, safe_Z} per atom
    const float* __restrict__ a_coef_ptr,  // 1
    const float* __restrict__ phi_c,       // 4
    const float* __restrict__ phi_e,       // 4
    float* __restrict__ out_acc,           // [N] accumulator (pre-zeroed)
    int nP)
{
    const int t  = blockIdx.x * 256 + threadIdx.x;
    const int p0 = t * 4;

    // per-thread uniforms (amortized over 4 pairs)
    const float ac_inv = rcpf_(fmaxf(fabsf(a_coef_ptr[0]), 1e-10f));
    float c0 = fabsf(phi_c[0]), c1 = fabsf(phi_c[1]);
    float c2 = fabsf(phi_c[2]), c3 = fabsf(phi_c[3]);
    const float cinv = rcpf_(fmaxf(c0 + c1 + c2 + c3, 1e-10f));
    c0 *= cinv; c1 *= cinv; c2 *= cinv; c3 *= cinv;
    const float e0 = fmaxf(fabsf(phi_e[0]), 1e-10f);
    const float e1 = fmaxf(fabsf(phi_e[1]), 1e-10f);
    const float e2 = fmaxf(fabsf(phi_e[2]), 1e-10f);
    const float e3 = fmaxf(fabsf(phi_e[3]), 1e-10f);

    float runsum = 0.0f;
    int   runkey = -1;

    if (p0 + 3 < nP) {
        // fully in-bounds fast path: vector loads
        const int4   ii4 = *reinterpret_cast<const int4*>(idx_i + p0);
        const int4   jj4 = *reinterpret_cast<const int4*>(idx_j + p0);
        const float4 bm4 = *reinterpret_cast<const float4*>(batch_mask + p0);
        const long   g   = (long)p0 * 3;
        const float4 da  = *reinterpret_cast<const float4*>(disp + g);
        const float4 db  = *reinterpret_cast<const float4*>(disp + g + 4);
        const float4 dc  = *reinterpret_cast<const float4*>(disp + g + 8);

        const int   ii[4] = {ii4.x, ii4.y, ii4.z, ii4.w};
        const int   jj[4] = {jj4.x, jj4.y, jj4.z, jj4.w};
        const float bm[4] = {bm4.x, bm4.y, bm4.z, bm4.w};
        const float dx[4] = {da.x, da.w, db.z, dc.y};
        const float dy[4] = {da.y, db.x, db.w, dc.z};
        const float dz[4] = {da.z, db.y, dc.x, dc.w};

        #pragma unroll
        for (int k = 0; k < 4; ++k) {
            float add = 1.0f - bm[k];
            float2 ti = tab[ii[k]];
            float2 tj = tab[jj[k]];
            float rep = pair_rep(dx[k] + add, dy[k] + add, dz[k] + add, bm[k],
                                 ti, tj, ac_inv, c0, c1, c2, c3, e0, e1, e2, e3);
            if (ii[k] == runkey) {
                runsum += rep;
            } else {
                if (runkey >= 0) atomicAdd(&out_acc[runkey], runsum);
                runkey = ii[k];
                runsum = rep;
            }
        }
    } else if (p0 < nP) {
        // scalar tail
        for (int k = 0; k < 4; ++k) {
            int p = p0 + k;
            if (p >= nP) break;
            float bmv = batch_mask[p];
            float add = 1.0f - bmv;
            int ik = idx_i[p], jk = idx_j[p];
            float2 ti = tab[ik];
            float2 tj = tab[jk];
            long g = (long)p * 3;
            float rep = pair_rep(disp[g] + add, disp[g + 1] + add, disp[g + 2] + add,
                                 bmv, ti, tj, ac_inv, c0, c1, c2, c3, e0, e1, e2, e3);
            if (ik == runkey) {
                runsum += rep;
            } else {
                if (runkey >= 0) atomicAdd(&out_acc[runkey], runsum);
                runkey = ik;
                runsum = rep;
            }
        }
    }

    // ---- wave-level segmented suffix-sum on (runkey, runsum); keys sorted.
    const int lane = threadIdx.x & 63;
    float v = runsum;
    int   key = runkey;
    #pragma unroll
    for (int d = 1; d < 64; d <<= 1) {
        float nv = __shfl_down(v, d);
        int   nk = __shfl_down(key, d);
        if (lane + d < 64 && nk == key) v += nv;
    }
    int pk = __shfl_up(key, 1);
    bool head = (lane == 0) || (pk != key);
    if (head && key >= 0) {
        atomicAdd(&out_acc[key], v);
    }
}

__global__ void zbl_epilogue(float* __restrict__ out,
                             const float* __restrict__ atom_mask, int n) {
    int i = blockIdx.x * blockDim.x + threadIdx.x;
    if (i >= n) return;
    float v = out[i] * atom_mask[i];
    v = fminf(fmaxf(v, 0.0f), 1e6f);
    if (!(v == v)) v = 0.0f;
    out[i] = v * 0.01f;
}

extern "C" void kernel_launch(void* const* d_in, const int* in_sizes, int n_in,
                              void* d_out, int out_size, void* d_ws, size_t ws_size,
                              hipStream_t stream) {
    const float* an         = (const float*)d_in[0];
    const float* disp       = (const float*)d_in[1];
    const int*   idx_i      = (const int*)d_in[2];
    const int*   idx_j      = (const int*)d_in[3];
    const float* atom_mask  = (const float*)d_in[4];
    const float* batch_mask = (const float*)d_in[5];
    // d_in[6] batch_segments, d_in[7] batch_size: unused by the reference math
    const float* a_coef     = (const float*)d_in[8];
    const float* a_exp      = (const float*)d_in[9];
    const float* phi_c      = (const float*)d_in[10];
    const float* phi_e      = (const float*)d_in[11];

    const int nA = in_sizes[0];
    const int nP = in_sizes[2];
    float* out = (float*)d_out;

    hipMemsetAsync(d_out, 0, (size_t)out_size * sizeof(float), stream);

    float2* tab = (float2*)d_ws;   // 100k float2 = 800 KB, ws is ample

    zbl_setup_tab<<<(nA + 255) / 256, 256, 0, stream>>>(an, a_exp, tab, nA);
    const int threads_needed = (nP + 3) / 4;
    zbl_pair_kernel<<<(threads_needed + 255) / 256, 256, 0, stream>>>(
        disp, idx_i, idx_j, batch_mask, tab, a_coef, phi_c, phi_e, out, nP);
    zbl_epilogue<<<(nA + 255) / 256, 256, 0, stream>>>(out, atom_mask, nA);
}

// Round 4
// 56.168 us; speedup vs baseline: 1.0380x; 1.0380x over previous
//
#include <hip/hip_runtime.h>
#include <math.h>

// ---------------------------------------------------------------------------
// ZBL repulsion, R4: 4 pairs/thread ILP + coalesced LDS staging for disp.
//  - block = 256 threads = 1024 pairs; disp staged via 3 coalesced float4
//    loads/thread -> linear LDS; readback 3x ds_read_b128 @ word-stride 12
//    (8 lanes tile all 32 banks: conflict-free)
//  - local run-merge on sorted idx_i; wave segmented reduce once per THREAD
//  - native exp2/rcp/rsq; rsq gives dist AND 1/dist in one trans op
// ---------------------------------------------------------------------------

#define LOG2E 1.4426950408889634f

static __device__ __forceinline__ float rcpf_(float x)  { return __builtin_amdgcn_rcpf(x); }
static __device__ __forceinline__ float rsqf_(float x)  { return __builtin_amdgcn_rsqf(x); }
static __device__ __forceinline__ float exp2f_(float x) { return __builtin_amdgcn_exp2f(x); }

__global__ void zbl_setup_tab(const float* __restrict__ an,
                              const float* __restrict__ a_exp_ptr,
                              float2* __restrict__ tab, int n) {
    int i = blockIdx.x * blockDim.x + threadIdx.x;
    if (i >= n) return;
    float ae = fabsf(a_exp_ptr[0]);
    float sa = fmaxf(an[i], 1e-6f);
    float z  = expf(logf(sa) * ae);   // one-time, libm precision
    if (!(z == z)) z = 1e-6f;
    z = fminf(z, 1e6f);
    tab[i] = make_float2(z, sa);
}

static __device__ __forceinline__ float pair_rep(
    float dx, float dy, float dz, float bm, float2 ti, float2 tj,
    float ac_inv, float c0, float c1, float c2, float c3,
    float e0, float e1, float e2, float e3)
{
    float d2   = fmaxf(dx * dx + dy * dy + dz * dz, 1e-20f);
    float rsq  = rsqf_(d2);
    float dist = d2 * rsq;                 // sqrt(d2); 1/dist == rsq

    // smooth_switch(dist,0,10) = 1/(1+exp(1/tc - 1/(1-tc)))
    float tt = dist * 0.1f;
    float tc = fminf(fmaxf(tt, 1e-9f), 1.0f - 1e-9f);
    float u  = (1.0f - 2.0f * tc) * rcpf_(tc - tc * tc);
    float s  = rcpf_(1.0f + exp2f_(u * LOG2E));
    float sw = (tt >= 1.0f) ? 1.0f : s;    // tt>0 always since dist>=1e-10

    float za_sum = ti.x + tj.x;
    float arg  = fminf(dist * za_sum * ac_inv, 1e6f);
    float narg = -arg * LOG2E;
    float phi  = c0 * exp2f_(e0 * narg) + c1 * exp2f_(e1 * narg) +
                 c2 * exp2f_(e2 * narg) + c3 * exp2f_(e3 * narg);
    phi = fminf(fmaxf(phi, 1e-30f), 1e6f);

    float cp   = fminf(ti.y * tj.y, 1e4f);
    float brep = fminf(0.5f * cp * rsq, 1e6f);
    float r    = brep * phi * fmaxf(sw, 1e-30f);
    r = fminf(fmaxf(r, 0.0f), 1e6f);
    if (!(r == r)) r = 0.0f;
    return r * bm;
}

__global__ __launch_bounds__(256) void zbl_pair_kernel(
    const float* __restrict__ disp,        // [P*3]
    const int*   __restrict__ idx_i,       // sorted
    const int*   __restrict__ idx_j,
    const float* __restrict__ batch_mask,  // [P]
    const float2* __restrict__ tab,        // {za, safe_Z} per atom
    const float* __restrict__ a_coef_ptr,  // 1
    const float* __restrict__ phi_c,       // 4
    const float* __restrict__ phi_e,       // 4
    float* __restrict__ out_acc,           // [N] accumulator (pre-zeroed)
    int nP)
{
    __shared__ float sdisp[1024 * 3];      // 12 KB

    const int tid       = threadIdx.x;
    const int base_pair = blockIdx.x * 1024;
    const int p0        = base_pair + tid * 4;
    const bool full     = (base_pair + 1024 <= nP);   // block-uniform

    // per-thread uniforms (amortized over 4 pairs)
    const float ac_inv = rcpf_(fmaxf(fabsf(a_coef_ptr[0]), 1e-10f));
    float c0 = fabsf(phi_c[0]), c1 = fabsf(phi_c[1]);
    float c2 = fabsf(phi_c[2]), c3 = fabsf(phi_c[3]);
    const float cinv = rcpf_(fmaxf(c0 + c1 + c2 + c3, 1e-10f));
    c0 *= cinv; c1 *= cinv; c2 *= cinv; c3 *= cinv;
    const float e0 = fmaxf(fabsf(phi_e[0]), 1e-10f);
    const float e1 = fmaxf(fabsf(phi_e[1]), 1e-10f);
    const float e2 = fmaxf(fabsf(phi_e[2]), 1e-10f);
    const float e3 = fmaxf(fabsf(phi_e[3]), 1e-10f);

    float runsum = 0.0f;
    int   runkey = -1;

    if (full) {
        // ---- coalesced stage: block window = 3072 floats = 768 float4
        {
            const float4* g4 = reinterpret_cast<const float4*>(disp + (long)base_pair * 3);
            float4* s4 = reinterpret_cast<float4*>(sdisp);
            #pragma unroll
            for (int s = 0; s < 3; ++s) {
                int idx = tid + s * 256;
                s4[idx] = g4[idx];
            }
        }
        __syncthreads();

        const int4   ii4 = *reinterpret_cast<const int4*>(idx_i + p0);
        const int4   jj4 = *reinterpret_cast<const int4*>(idx_j + p0);
        const float4 bm4 = *reinterpret_cast<const float4*>(batch_mask + p0);

        // own 12 floats: word-stride 12 -> conflict-free b128 reads
        const float4* s4 = reinterpret_cast<const float4*>(sdisp + tid * 12);
        const float4 da = s4[0];
        const float4 db = s4[1];
        const float4 dc = s4[2];

        const int   ii[4] = {ii4.x, ii4.y, ii4.z, ii4.w};
        const int   jj[4] = {jj4.x, jj4.y, jj4.z, jj4.w};
        const float bm[4] = {bm4.x, bm4.y, bm4.z, bm4.w};
        const float dx[4] = {da.x, da.w, db.z, dc.y};
        const float dy[4] = {da.y, db.x, db.w, dc.z};
        const float dz[4] = {da.z, db.y, dc.x, dc.w};

        #pragma unroll
        for (int k = 0; k < 4; ++k) {
            float add = 1.0f - bm[k];
            float2 ti = tab[ii[k]];
            float2 tj = tab[jj[k]];
            float rep = pair_rep(dx[k] + add, dy[k] + add, dz[k] + add, bm[k],
                                 ti, tj, ac_inv, c0, c1, c2, c3, e0, e1, e2, e3);
            if (ii[k] == runkey) {
                runsum += rep;
            } else {
                if (runkey >= 0) atomicAdd(&out_acc[runkey], runsum);
                runkey = ii[k];
                runsum = rep;
            }
        }
    } else if (p0 < nP) {
        // scalar tail (last block only)
        for (int k = 0; k < 4; ++k) {
            int p = p0 + k;
            if (p >= nP) break;
            float bmv = batch_mask[p];
            float add = 1.0f - bmv;
            int ik = idx_i[p], jk = idx_j[p];
            float2 ti = tab[ik];
            float2 tj = tab[jk];
            long g = (long)p * 3;
            float rep = pair_rep(disp[g] + add, disp[g + 1] + add, disp[g + 2] + add,
                                 bmv, ti, tj, ac_inv, c0, c1, c2, c3, e0, e1, e2, e3);
            if (ik == runkey) {
                runsum += rep;
            } else {
                if (runkey >= 0) atomicAdd(&out_acc[runkey], runsum);
                runkey = ik;
                runsum = rep;
            }
        }
    }

    // ---- wave-level segmented suffix-sum on (runkey, runsum); keys sorted.
    const int lane = threadIdx.x & 63;
    float v = runsum;
    int   key = runkey;
    #pragma unroll
    for (int d = 1; d < 64; d <<= 1) {
        float nv = __shfl_down(v, d);
        int   nk = __shfl_down(key, d);
        if (lane + d < 64 && nk == key) v += nv;
    }
    int pk = __shfl_up(key, 1);
    bool head = (lane == 0) || (pk != key);
    if (head && key >= 0) {
        atomicAdd(&out_acc[key], v);
    }
}

__global__ void zbl_epilogue(float* __restrict__ out,
                             const float* __restrict__ atom_mask, int n) {
    int i = blockIdx.x * blockDim.x + threadIdx.x;
    if (i >= n) return;
    float v = out[i] * atom_mask[i];
    v = fminf(fmaxf(v, 0.0f), 1e6f);
    if (!(v == v)) v = 0.0f;
    out[i] = v * 0.01f;
}

extern "C" void kernel_launch(void* const* d_in, const int* in_sizes, int n_in,
                              void* d_out, int out_size, void* d_ws, size_t ws_size,
                              hipStream_t stream) {
    const float* an         = (const float*)d_in[0];
    const float* disp       = (const float*)d_in[1];
    const int*   idx_i      = (const int*)d_in[2];
    const int*   idx_j      = (const int*)d_in[3];
    const float* atom_mask  = (const float*)d_in[4];
    const float* batch_mask = (const float*)d_in[5];
    // d_in[6] batch_segments, d_in[7] batch_size: unused by the reference math
    const float* a_coef     = (const float*)d_in[8];
    const float* a_exp      = (const float*)d_in[9];
    const float* phi_c      = (const float*)d_in[10];
    const float* phi_e      = (const float*)d_in[11];

    const int nA = in_sizes[0];
    const int nP = in_sizes[2];
    float* out = (float*)d_out;

    hipMemsetAsync(d_out, 0, (size_t)out_size * sizeof(float), stream);

    float2* tab = (float2*)d_ws;   // 100k float2 = 800 KB, ws is ample

    zbl_setup_tab<<<(nA + 255) / 256, 256, 0, stream>>>(an, a_exp, tab, nA);
    const int nblocks = (nP + 1023) / 1024;
    zbl_pair_kernel<<<nblocks, 256, 0, stream>>>(
        disp, idx_i, idx_j, batch_mask, tab, a_coef, phi_c, phi_e, out, nP);
    zbl_epilogue<<<(nA + 255) / 256, 256, 0, stream>>>(out, atom_mask, nA);
}

// Round 5
// 54.159 us; speedup vs baseline: 1.0765x; 1.0371x over previous
//
#include <hip/hip_runtime.h>
#include <math.h>

// ---------------------------------------------------------------------------
// ZBL repulsion, R5: max-TLP latency-hiding round.
//  - 1 pair/thread (100k waves), NO LDS staging, NO barrier
//  - disp read as 3 stride-3-dword loads (12-line span per inst, L1-backed)
//  - idx loads issued FIRST so tab gathers overlap disp/bm stream latency
//  - native exp2/rcp/rsq lean math (5 exp2 per pair)
//  - wave segmented scan on sorted idx_i, one atomic per run head
// ---------------------------------------------------------------------------

#define LOG2E 1.4426950408889634f

static __device__ __forceinline__ float rcpf_(float x)  { return __builtin_amdgcn_rcpf(x); }
static __device__ __forceinline__ float rsqf_(float x)  { return __builtin_amdgcn_rsqf(x); }
static __device__ __forceinline__ float exp2f_(float x) { return __builtin_amdgcn_exp2f(x); }

__global__ void zbl_setup_tab(const float* __restrict__ an,
                              const float* __restrict__ a_exp_ptr,
                              float2* __restrict__ tab, int n) {
    int i = blockIdx.x * blockDim.x + threadIdx.x;
    if (i >= n) return;
    float ae = fabsf(a_exp_ptr[0]);
    float sa = fmaxf(an[i], 1e-6f);
    float z  = expf(logf(sa) * ae);   // one-time, libm precision
    if (!(z == z)) z = 1e-6f;
    z = fminf(z, 1e6f);
    tab[i] = make_float2(z, sa);
}

__global__ __launch_bounds__(256) void zbl_pair_kernel(
    const float* __restrict__ disp,        // [P*3]
    const int*   __restrict__ idx_i,       // sorted
    const int*   __restrict__ idx_j,
    const float* __restrict__ batch_mask,  // [P]
    const float2* __restrict__ tab,        // {za, safe_Z} per atom
    const float* __restrict__ a_coef_ptr,  // 1
    const float* __restrict__ phi_c,       // 4
    const float* __restrict__ phi_e,       // 4
    float* __restrict__ out_acc,           // [N] accumulator (pre-zeroed)
    int nP)
{
    const int p = blockIdx.x * 256 + threadIdx.x;

    float rep = 0.0f;
    int   key = -1;

    if (p < nP) {
        // ---- issue order matters: idx first (gathers depend on them),
        //      then the streaming loads; all stay in one vmcnt window.
        const int ii = idx_i[p];
        const int jj = idx_j[p];
        const long g = (long)p * 3;
        const float dxr = disp[g + 0];
        const float dyr = disp[g + 1];
        const float dzr = disp[g + 2];
        const float bm  = batch_mask[p];
        const float2 ti = tab[ii];
        const float2 tj = tab[jj];

        // uniforms (scalar loads, hoisted by compiler)
        const float ac_inv = rcpf_(fmaxf(fabsf(a_coef_ptr[0]), 1e-10f));
        float c0 = fabsf(phi_c[0]), c1 = fabsf(phi_c[1]);
        float c2 = fabsf(phi_c[2]), c3 = fabsf(phi_c[3]);
        const float cinv = rcpf_(fmaxf(c0 + c1 + c2 + c3, 1e-10f));
        c0 *= cinv; c1 *= cinv; c2 *= cinv; c3 *= cinv;
        const float e0 = fmaxf(fabsf(phi_e[0]), 1e-10f);
        const float e1 = fmaxf(fabsf(phi_e[1]), 1e-10f);
        const float e2 = fmaxf(fabsf(phi_e[2]), 1e-10f);
        const float e3 = fmaxf(fabsf(phi_e[3]), 1e-10f);

        const float add = 1.0f - bm;
        const float dx = dxr + add, dy = dyr + add, dz = dzr + add;

        float d2   = fmaxf(dx * dx + dy * dy + dz * dz, 1e-20f);
        float rsq  = rsqf_(d2);
        float dist = d2 * rsq;                 // sqrt(d2); 1/dist == rsq

        // smooth_switch(dist,0,10) = 1/(1+exp(1/tc - 1/(1-tc)))
        float tt = dist * 0.1f;
        float tc = fminf(fmaxf(tt, 1e-9f), 1.0f - 1e-9f);
        float u  = (1.0f - 2.0f * tc) * rcpf_(tc - tc * tc);
        float s  = rcpf_(1.0f + exp2f_(u * LOG2E));
        float sw = (tt >= 1.0f) ? 1.0f : s;    // tt>0 always since dist>=1e-10

        float za_sum = ti.x + tj.x;
        float arg  = fminf(dist * za_sum * ac_inv, 1e6f);
        float narg = -arg * LOG2E;
        float phi  = c0 * exp2f_(e0 * narg) + c1 * exp2f_(e1 * narg) +
                     c2 * exp2f_(e2 * narg) + c3 * exp2f_(e3 * narg);
        phi = fminf(fmaxf(phi, 1e-30f), 1e6f);

        float cp   = fminf(ti.y * tj.y, 1e4f);
        float brep = fminf(0.5f * cp * rsq, 1e6f);
        float r    = brep * phi * fmaxf(sw, 1e-30f);
        r = fminf(fmaxf(r, 0.0f), 1e6f);
        if (!(r == r)) r = 0.0f;
        rep = r * bm;
        key = ii;
    }

    // ---- wave-level segmented suffix-sum on sorted keys
    const int lane = threadIdx.x & 63;
    float v = rep;
    #pragma unroll
    for (int d = 1; d < 64; d <<= 1) {
        float nv = __shfl_down(v, d);
        int   nk = __shfl_down(key, d);
        if (lane + d < 64 && nk == key) v += nv;
    }
    int pk = __shfl_up(key, 1);
    bool head = (lane == 0) || (pk != key);
    if (head && key >= 0) {
        atomicAdd(&out_acc[key], v);
    }
}

__global__ void zbl_epilogue(float* __restrict__ out,
                             const float* __restrict__ atom_mask, int n) {
    int i = blockIdx.x * blockDim.x + threadIdx.x;
    if (i >= n) return;
    float v = out[i] * atom_mask[i];
    v = fminf(fmaxf(v, 0.0f), 1e6f);
    if (!(v == v)) v = 0.0f;
    out[i] = v * 0.01f;
}

extern "C" void kernel_launch(void* const* d_in, const int* in_sizes, int n_in,
                              void* d_out, int out_size, void* d_ws, size_t ws_size,
                              hipStream_t stream) {
    const float* an         = (const float*)d_in[0];
    const float* disp       = (const float*)d_in[1];
    const int*   idx_i      = (const int*)d_in[2];
    const int*   idx_j      = (const int*)d_in[3];
    const float* atom_mask  = (const float*)d_in[4];
    const float* batch_mask = (const float*)d_in[5];
    // d_in[6] batch_segments, d_in[7] batch_size: unused by the reference math
    const float* a_coef     = (const float*)d_in[8];
    const float* a_exp      = (const float*)d_in[9];
    const float* phi_c      = (const float*)d_in[10];
    const float* phi_e      = (const float*)d_in[11];

    const int nA = in_sizes[0];
    const int nP = in_sizes[2];
    float* out = (float*)d_out;

    hipMemsetAsync(d_out, 0, (size_t)out_size * sizeof(float), stream);

    float2* tab = (float2*)d_ws;   // 100k float2 = 800 KB, ws is ample

    zbl_setup_tab<<<(nA + 255) / 256, 256, 0, stream>>>(an, a_exp, tab, nA);
    zbl_pair_kernel<<<(nP + 255) / 256, 256, 0, stream>>>(
        disp, idx_i, idx_j, batch_mask, tab, a_coef, phi_c, phi_e, out, nP);
    zbl_epilogue<<<(nA + 255) / 256, 256, 0, stream>>>(out, atom_mask, nA);
}